// Round 1
// baseline (150.221 us; speedup 1.0000x reference)
//
#include <hip/hip_runtime.h>
#include <cstddef>
#include <cstdint>

#define SPTS 512
#define PPS  512
#define KFPS 10
#define NMSK 128
#define HH 512
#define WW 512
#define HWPIX (HH*WW)
#define FDIM 32
#define TOPK_SEL 10
#define NMASK_TOP 5

// ---------- mask dtype handling (u8 / int32 / float32) ----------
__device__ __forceinline__ unsigned mask_val(const void* raw, long long idx, int mode) {
    if (mode == 0) return ((const unsigned char*)raw)[idx] ? 1u : 0u;
    if (mode == 1) return ((const int*)raw)[idx] ? 1u : 0u;
    return (((const float*)raw)[idx] != 0.0f) ? 1u : 0u;
}

// Detect the element layout of the bool mask array from its first 4096 bytes.
// u8 bool: nonzero bytes appear at offsets %4==1 (p~0.15 each -> certain).
// f32 0/1: nonzero only at %4==2 (0x80) and %4==3 (0x3F).
// int32 0/1: nonzero only at %4==0.
__global__ void k_detect(const unsigned char* raw, int* cfg) {
    __shared__ int any1, any23;
    if (threadIdx.x == 0) { any1 = 0; any23 = 0; }
    __syncthreads();
    int l1 = 0, l23 = 0;
    for (int i = threadIdx.x; i < 4096; i += blockDim.x) {
        unsigned char b = raw[i];
        if (b) { int r = i & 3; if (r == 1) l1 = 1; else if (r >= 2) l23 = 1; }
    }
    if (l1)  atomicOr(&any1, 1);
    if (l23) atomicOr(&any23, 1);
    __syncthreads();
    if (threadIdx.x == 0) cfg[0] = any1 ? 0 : (any23 ? 2 : 1);
}

// ---------- repack masks: maskbits[pix] = 128 bits over masks ----------
__global__ void k_repack(const void* raw, const int* cfg, unsigned* maskbits) {
    int pix = blockIdx.x * blockDim.x + threadIdx.x;
    if (pix >= HWPIX) return;
    int mode = cfg[0];
    unsigned w0 = 0, w1 = 0, w2 = 0, w3 = 0;
#pragma unroll 4
    for (int m = 0; m < NMSK; ++m) {
        unsigned v = mask_val(raw, (long long)m * HWPIX + pix, mode);
        if (m < 32)       w0 |= v << m;
        else if (m < 64)  w1 |= v << (m - 32);
        else if (m < 96)  w2 |= v << (m - 64);
        else              w3 |= v << (m - 96);
    }
    uint4 w; w.x = w0; w.y = w1; w.z = w2; w.w = w3;
    *((uint4*)(maskbits + (size_t)pix * 4)) = w;
}

// ---------- FPS per superpoint; writes rep coordinates ----------
__global__ void __launch_bounds__(PPS) k_fps(const float* pcds, float* reps) {
    int s = blockIdx.x;
    int t = threadIdx.x;
    const float* base = pcds + (size_t)s * PPS * 3;
    float x = base[t * 3 + 0], y = base[t * 3 + 1], z = base[t * 3 + 2];
    float ax = base[0], ay = base[1], az = base[2];
    float dx = x - ax, dy = y - ay, dz = z - az;
    float dist = sqrtf(dx * dx + dy * dy + dz * dz);
    if (t == 0) {
        reps[((size_t)s * KFPS + 0) * 3 + 0] = ax;
        reps[((size_t)s * KFPS + 0) * 3 + 1] = ay;
        reps[((size_t)s * KFPS + 0) * 3 + 2] = az;
    }
    __shared__ float swv[8];
    __shared__ int   swi[8];
    __shared__ int   sIdx;
    for (int kk = 1; kk < KFPS; ++kk) {
        float v = dist; int idx = t;
        // wave argmax, tie -> lower index (matches jnp.argmax first-max)
        for (int off = 32; off >= 1; off >>= 1) {
            float ov = __shfl_xor(v, off);
            int   oi = __shfl_xor(idx, off);
            if (ov > v || (ov == v && oi < idx)) { v = ov; idx = oi; }
        }
        int wave = t >> 6, lane = t & 63;
        if (lane == 0) { swv[wave] = v; swi[wave] = idx; }
        __syncthreads();
        if (t == 0) {
            float bv = swv[0]; int bi = swi[0];
            for (int w = 1; w < 8; ++w)
                if (swv[w] > bv || (swv[w] == bv && swi[w] < bi)) { bv = swv[w]; bi = swi[w]; }
            sIdx = bi;
        }
        __syncthreads();
        int bi = sIdx;
        float px = base[bi * 3 + 0], py = base[bi * 3 + 1], pz = base[bi * 3 + 2];
        float ex = x - px, ey = y - py, ez = z - pz;
        float d = sqrtf(ex * ex + ey * ey + ez * ez);
        dist = fminf(dist, d);
        if (t == 0) {
            reps[((size_t)s * KFPS + kk) * 3 + 0] = px;
            reps[((size_t)s * KFPS + kk) * 3 + 1] = py;
            reps[((size_t)s * KFPS + kk) * 3 + 2] = pz;
        }
        __syncthreads();
    }
}

// ---------- per-superpoint per-mask coverage counts ----------
__global__ void __launch_bounds__(PPS) k_counts(const int* mapping, const unsigned* maskbits,
                                                const void* raw, const int* cfg, int packed,
                                                int* counts) {
    int s = blockIdx.x;
    int t = threadIdx.x;
    __shared__ int cnt[NMSK];
    if (t < NMSK) cnt[t] = 0;
    __syncthreads();
    int i = s * PPS + t;
    int y = mapping[i * 4 + 1]; y = min(max(y, 0), HH - 1);
    int x = mapping[i * 4 + 2]; x = min(max(x, 0), WW - 1);
    bool vis = (mapping[i * 4 + 3] == 1);
    unsigned w0 = 0, w1 = 0, w2 = 0, w3 = 0;
    if (vis) {
        if (packed) {
            uint4 v = *((const uint4*)(maskbits + (size_t)(y * WW + x) * 4));
            w0 = v.x; w1 = v.y; w2 = v.z; w3 = v.w;
        } else {
            int mode = cfg[0];
            long long pix = (long long)y * WW + x;
            for (int m = 0; m < NMSK; ++m) {
                unsigned v = mask_val(raw, (long long)m * HWPIX + pix, mode);
                if (m < 32)       w0 |= v << m;
                else if (m < 64)  w1 |= v << (m - 32);
                else if (m < 96)  w2 |= v << (m - 64);
                else              w3 |= v << (m - 96);
            }
        }
    }
    int lane = t & 63;
    unsigned ww[4] = { w0, w1, w2, w3 };
#pragma unroll
    for (int m = 0; m < NMSK; ++m) {
        unsigned bit = (ww[m >> 5] >> (m & 31)) & 1u;
        unsigned long long bal = __ballot((int)bit);
        if (lane == 0) atomicAdd(&cnt[m], (int)__popcll(bal));
    }
    __syncthreads();
    if (t < NMSK) counts[s * NMSK + t] = cnt[t];
}

// ---------- stable top-k selection per mask + contrib bits + frac_kept ----------
__global__ void __launch_bounds__(SPTS) k_topk(const int* counts, unsigned* contrib, float* frac_kept) {
    int m = blockIdx.x;   // mask id
    int s = threadIdx.x;  // superpoint id
    __shared__ int cl[SPTS];
    cl[s] = counts[s * NMSK + m];
    __syncthreads();
    int c = cl[s];
    int rank = 0;
    for (int s2 = 0; s2 < SPTS; ++s2) {
        int c2 = cl[s2];
        rank += (c2 > c || (c2 == c && s2 < s)) ? 1 : 0;
    }
    bool sel = (rank < TOPK_SEL);
    float frac = (float)c / 512.0f;   // counts / (P + 1e-6) == counts / 512.0f in fp32
    frac_kept[s * NMSK + m] = sel ? frac : 0.0f;
    if (sel && frac >= 0.2f)
        atomicOr(&contrib[s * 4 + (m >> 5)], 1u << (m & 31));
}

// ---------- superpoint features (mean over P, L2-normalized) ----------
__global__ void __launch_bounds__(256) k_feats(const float* feas, float* feats) {
    int s = blockIdx.x;
    int t = threadIdx.x;        // 256 threads
    int d = t & 31, pr = t >> 5; // 8 point-groups x 32 dims
    const float* base = feas + (size_t)s * PPS * FDIM;
    float acc = 0.0f;
    for (int p = pr; p < PPS; p += 8) acc += base[p * FDIM + d];
    __shared__ float part[8][FDIM];
    part[pr][d] = acc;
    __syncthreads();
    if (t < FDIM) {
        float sum = 0.0f;
        for (int g = 0; g < 8; ++g) sum += part[g][t];
        float f = sum / 512.0f;   // / (P + 1e-6) == 512.0f in fp32
        float sq = f * f;
        for (int off = 16; off >= 1; off >>= 1) sq += __shfl_xor(sq, off);
        float nrm = sqrtf(sq);
        feats[s * FDIM + t] = f / fmaxf(nrm, 1e-12f);
    }
}

// ---------- base adjacency from rep-set min distances ----------
__global__ void __launch_bounds__(256) k_adj(const float* reps, float* out) {
    int idx = blockIdx.x * blockDim.x + threadIdx.x;
    int i = idx >> 9, j = idx & 511;
    __shared__ float ri[KFPS * 3];
    __shared__ float sqi[KFPS];
    if (threadIdx.x < KFPS * 3) ri[threadIdx.x] = reps[(size_t)i * KFPS * 3 + threadIdx.x];
    __syncthreads();
    if (threadIdx.x < KFPS) {
        float X = ri[threadIdx.x * 3], Y = ri[threadIdx.x * 3 + 1], Z = ri[threadIdx.x * 3 + 2];
        sqi[threadIdx.x] = X * X + Y * Y + Z * Z;
    }
    __syncthreads();
    float rjx[KFPS], rjy[KFPS], rjz[KFPS], sqj[KFPS];
    const float* rp = reps + (size_t)j * KFPS * 3;
#pragma unroll
    for (int b = 0; b < KFPS; ++b) {
        float X = rp[b * 3], Y = rp[b * 3 + 1], Z = rp[b * 3 + 2];
        rjx[b] = X; rjy[b] = Y; rjz[b] = Z;
        sqj[b] = X * X + Y * Y + Z * Z;
    }
    float mn = 1e30f;
#pragma unroll
    for (int a = 0; a < KFPS; ++a) {
        float ax = ri[a * 3], ay = ri[a * 3 + 1], az = ri[a * 3 + 2];
        float sa = sqi[a];
#pragma unroll
        for (int b = 0; b < KFPS; ++b) {
            float dot = ax * rjx[b] + ay * rjy[b] + az * rjz[b];
            float d2 = (sa + sqj[b]) - 2.0f * dot;   // mirror reference formula
            mn = fminf(mn, d2);
        }
    }
    float dmin = sqrtf(fmaxf(mn, 1e-12f));
    out[idx] = (dmin < 0.2f && i != j) ? expf(-dmin) : 0.0f;
}

// ---------- modulate adjacency by mask-overlap IoU and feature similarity ----------
__global__ void __launch_bounds__(256) k_mod(float* out, const unsigned* contrib, const float* feats) {
    int idx = blockIdx.x * blockDim.x + threadIdx.x;
    int i = idx >> 9, j = idx & 511;
    float a = out[idx];
    if (a <= 0.0f) return;
    uint4 c4i = *((const uint4*)(contrib + (size_t)i * 4));
    uint4 c4j = *((const uint4*)(contrib + (size_t)j * 4));
    unsigned cia[4] = { c4i.x, c4i.y, c4i.z, c4i.w };
    unsigned cja[4] = { c4j.x, c4j.y, c4j.z, c4j.w };
    int taken = 0, inter = 0, uni = 0;
#pragma unroll
    for (int w = 0; w < 4; ++w) {
        unsigned u = cia[w] | cja[w];
        unsigned both = cia[w] & cja[w];
        while (u && taken < NMASK_TOP) {
            unsigned bit = u & (~u + 1u);  // lowest set bit -> ascending index order
            uni++;
            if (both & bit) inter++;
            u ^= bit; taken++;
        }
    }
    float overlap = (float)inter / ((float)uni + 1e-6f);
    const float* fi = feats + (size_t)i * FDIM;
    const float* fj = feats + (size_t)j * FDIM;
    float dot = 0.0f;
#pragma unroll
    for (int d = 0; d < FDIM; ++d) dot += fi[d] * fj[d];
    float sim = (dot + 1.0f) / 2.0f;
    sim = fminf(fmaxf(sim, 0.0f), 1.0f);
    if (sim < 0.5f) sim = 1.0f;
    float mod = overlap * sim;
    out[idx] = fmaxf(mod, a);
}

// ---------- superpoint confidence ----------
__global__ void __launch_bounds__(256) k_conf(const float* frac_kept, const float* sam, float* out) {
    int s = blockIdx.x * blockDim.x + threadIdx.x;
    if (s >= SPTS) return;
    float sw = 0.0f, sf = 0.0f;
    for (int m = 0; m < NMSK; ++m) {
        float fk = frac_kept[s * NMSK + m];
        sw += fk * sam[m];
        sf += fk;
    }
    out[(size_t)SPTS * SPTS + s] = fmaxf(sw / (sf + 1e-6f), 0.0f);
}

extern "C" void kernel_launch(void* const* d_in, const int* in_sizes, int n_in,
                              void* d_out, int out_size, void* d_ws, size_t ws_size,
                              hipStream_t stream) {
    const float* pcds    = (const float*)d_in[0];
    // d_in[1] = spt_labels (unused: superpoints are contiguous groups of P)
    const void*  masks   = d_in[2];
    const int*   mapping = (const int*)d_in[3];
    const float* sam     = (const float*)d_in[4];
    const float* feas    = (const float*)d_in[5];
    float* out = (float*)d_out;

    char* ws = (char*)d_ws;
    size_t off = 0;
    auto take = [&](size_t bytes) -> void* {
        void* p = ws + off;
        off += (bytes + 255) & ~(size_t)255;
        return p;
    };
    int*      cfg       = (int*)take(256);
    float*    reps      = (float*)take((size_t)SPTS * KFPS * 3 * sizeof(float));
    int*      counts    = (int*)take((size_t)SPTS * NMSK * sizeof(int));
    unsigned* contrib   = (unsigned*)take((size_t)SPTS * 4 * sizeof(unsigned));
    float*    frac_kept = (float*)take((size_t)SPTS * NMSK * sizeof(float));
    float*    feats     = (float*)take((size_t)SPTS * FDIM * sizeof(float));
    unsigned* maskbits  = (unsigned*)take((size_t)HWPIX * 4 * sizeof(unsigned));
    size_t need_packed = off;
    int packed = (ws_size >= need_packed) ? 1 : 0;

    k_detect<<<1, 256, 0, stream>>>((const unsigned char*)masks, cfg);
    hipMemsetAsync(contrib, 0, (size_t)SPTS * 4 * sizeof(unsigned), stream);
    if (packed)
        k_repack<<<HWPIX / 256, 256, 0, stream>>>(masks, cfg, maskbits);
    k_fps<<<SPTS, PPS, 0, stream>>>(pcds, reps);
    k_counts<<<SPTS, PPS, 0, stream>>>(mapping, maskbits, masks, cfg, packed, counts);
    k_topk<<<NMSK, SPTS, 0, stream>>>(counts, contrib, frac_kept);
    k_feats<<<SPTS, 256, 0, stream>>>(feas, feats);
    k_adj<<<(SPTS * SPTS) / 256, 256, 0, stream>>>(reps, out);
    k_mod<<<(SPTS * SPTS) / 256, 256, 0, stream>>>(out, contrib, feats);
    k_conf<<<2, 256, 0, stream>>>(frac_kept, sam, out);
}

// Round 2
// 123.330 us; speedup vs baseline: 1.2180x; 1.2180x over previous
//
#include <hip/hip_runtime.h>
#include <cstddef>
#include <cstdint>

#define SPTS 512
#define PPS  512
#define KFPS 10
#define NMSK 128
#define HH 512
#define WW 512
#define HWPIX (HH*WW)
#define FDIM 32
#define TOPK_SEL 10
#define NMASK_TOP 5

// ---------- mask dtype handling (u8 / int32 / float32) ----------
__device__ __forceinline__ unsigned mask_val(const void* raw, long long idx, int mode) {
    if (mode == 0) return ((const unsigned char*)raw)[idx] ? 1u : 0u;
    if (mode == 1) return ((const int*)raw)[idx] ? 1u : 0u;
    return (((const float*)raw)[idx] != 0.0f) ? 1u : 0u;
}

// Detect the element layout of the bool mask array from its first 4096 bytes.
// u8 bool: nonzero bytes appear at offsets %4==1 (p~0.15 each -> certain).
// f32 0/1: nonzero only at %4==2 (0x80) and %4==3 (0x3F).
// int32 0/1: nonzero only at %4==0.
__global__ void k_detect(const unsigned char* raw, int* cfg) {
    __shared__ int any1, any23;
    if (threadIdx.x == 0) { any1 = 0; any23 = 0; }
    __syncthreads();
    int l1 = 0, l23 = 0;
    for (int i = threadIdx.x; i < 4096; i += blockDim.x) {
        unsigned char b = raw[i];
        if (b) { int r = i & 3; if (r == 1) l1 = 1; else if (r >= 2) l23 = 1; }
    }
    if (l1)  atomicOr(&any1, 1);
    if (l23) atomicOr(&any23, 1);
    __syncthreads();
    if (threadIdx.x == 0) cfg[0] = any1 ? 0 : (any23 ? 2 : 1);
}

// ---------- repack masks: maskbits[pix][0..3] = 128 bits over masks ----------
// Grid: 512 blocks x 256 threads. blockIdx encodes (pixel-tile, mask-half).
// Each thread owns 4 consecutive pixels and one 64-mask half -> uint2 out.
// u8 path: one dword load = 4 pixels of one mask (bool bytes are exactly 0/1).
// dword path (int32/f32): one uint4 load = 4 pixels; nonzero test via int bits.
__global__ void __launch_bounds__(256) k_repack_fast(const void* raw, const int* cfg,
                                                     unsigned* maskbits) {
    int mode = cfg[0];
    int bid = blockIdx.x;
    int half  = bid & 1;      // 0: masks 0..63, 1: masks 64..127
    int ptile = bid >> 1;     // 256 tiles x 1024 pixels
    int pix0 = ptile * 1024 + threadIdx.x * 4;
    unsigned w0[4] = {0, 0, 0, 0};   // masks [half*64, half*64+32)
    unsigned w1[4] = {0, 0, 0, 0};   // masks [half*64+32, half*64+64)
    if (mode == 0) {
        const unsigned char* base = (const unsigned char*)raw + (size_t)half * 64 * HWPIX + pix0;
#pragma unroll
        for (int m = 0; m < 64; ++m) {
            unsigned v = *(const unsigned*)(base + (size_t)m * HWPIX);
            unsigned sh = m & 31;
#pragma unroll
            for (int p = 0; p < 4; ++p) {
                unsigned bit = (v >> (8 * p)) & 1u;
                if (m < 32) w0[p] |= bit << sh; else w1[p] |= bit << sh;
            }
        }
    } else {
        const unsigned* base = (const unsigned*)raw + (size_t)half * 64 * HWPIX + pix0;
#pragma unroll 16
        for (int m = 0; m < 64; ++m) {
            uint4 v = *(const uint4*)(base + (size_t)m * HWPIX);
            unsigned sh = m & 31;
            unsigned b0 = (v.x != 0u), b1 = (v.y != 0u), b2 = (v.z != 0u), b3 = (v.w != 0u);
            if (m < 32) {
                w0[0] |= b0 << sh; w0[1] |= b1 << sh; w0[2] |= b2 << sh; w0[3] |= b3 << sh;
            } else {
                w1[0] |= b0 << sh; w1[1] |= b1 << sh; w1[2] |= b2 << sh; w1[3] |= b3 << sh;
            }
        }
    }
#pragma unroll
    for (int p = 0; p < 4; ++p) {
        uint2 o; o.x = w0[p]; o.y = w1[p];
        *(uint2*)(maskbits + (size_t)(pix0 + p) * 4 + half * 2) = o;
    }
}

// ---------- FPS per superpoint; writes rep coordinates ----------
__global__ void __launch_bounds__(PPS) k_fps(const float* pcds, float* reps) {
    int s = blockIdx.x;
    int t = threadIdx.x;
    const float* base = pcds + (size_t)s * PPS * 3;
    float x = base[t * 3 + 0], y = base[t * 3 + 1], z = base[t * 3 + 2];
    float ax = base[0], ay = base[1], az = base[2];
    float dx = x - ax, dy = y - ay, dz = z - az;
    float dist = sqrtf(dx * dx + dy * dy + dz * dz);
    if (t == 0) {
        reps[((size_t)s * KFPS + 0) * 3 + 0] = ax;
        reps[((size_t)s * KFPS + 0) * 3 + 1] = ay;
        reps[((size_t)s * KFPS + 0) * 3 + 2] = az;
    }
    __shared__ float swv[8];
    __shared__ int   swi[8];
    __shared__ int   sIdx;
    for (int kk = 1; kk < KFPS; ++kk) {
        float v = dist; int idx = t;
        // wave argmax, tie -> lower index (matches jnp.argmax first-max)
        for (int off = 32; off >= 1; off >>= 1) {
            float ov = __shfl_xor(v, off);
            int   oi = __shfl_xor(idx, off);
            if (ov > v || (ov == v && oi < idx)) { v = ov; idx = oi; }
        }
        int wave = t >> 6, lane = t & 63;
        if (lane == 0) { swv[wave] = v; swi[wave] = idx; }
        __syncthreads();
        if (t == 0) {
            float bv = swv[0]; int bi = swi[0];
            for (int w = 1; w < 8; ++w)
                if (swv[w] > bv || (swv[w] == bv && swi[w] < bi)) { bv = swv[w]; bi = swi[w]; }
            sIdx = bi;
        }
        __syncthreads();
        int bi = sIdx;
        float px = base[bi * 3 + 0], py = base[bi * 3 + 1], pz = base[bi * 3 + 2];
        float ex = x - px, ey = y - py, ez = z - pz;
        float d = sqrtf(ex * ex + ey * ey + ez * ez);
        dist = fminf(dist, d);
        if (t == 0) {
            reps[((size_t)s * KFPS + kk) * 3 + 0] = px;
            reps[((size_t)s * KFPS + kk) * 3 + 1] = py;
            reps[((size_t)s * KFPS + kk) * 3 + 2] = pz;
        }
        __syncthreads();
    }
}

// ---------- per-superpoint per-mask coverage counts ----------
__global__ void __launch_bounds__(PPS) k_counts(const int* mapping, const unsigned* maskbits,
                                                const void* raw, const int* cfg, int packed,
                                                int* counts) {
    int s = blockIdx.x;
    int t = threadIdx.x;
    __shared__ int cnt[NMSK];
    if (t < NMSK) cnt[t] = 0;
    __syncthreads();
    int i = s * PPS + t;
    int y = mapping[i * 4 + 1]; y = min(max(y, 0), HH - 1);
    int x = mapping[i * 4 + 2]; x = min(max(x, 0), WW - 1);
    bool vis = (mapping[i * 4 + 3] == 1);
    unsigned w0 = 0, w1 = 0, w2 = 0, w3 = 0;
    if (vis) {
        if (packed) {
            uint4 v = *((const uint4*)(maskbits + (size_t)(y * WW + x) * 4));
            w0 = v.x; w1 = v.y; w2 = v.z; w3 = v.w;
        } else {
            int mode = cfg[0];
            long long pix = (long long)y * WW + x;
            for (int m = 0; m < NMSK; ++m) {
                unsigned v = mask_val(raw, (long long)m * HWPIX + pix, mode);
                if (m < 32)       w0 |= v << m;
                else if (m < 64)  w1 |= v << (m - 32);
                else if (m < 96)  w2 |= v << (m - 64);
                else              w3 |= v << (m - 96);
            }
        }
    }
    int lane = t & 63;
    unsigned ww[4] = { w0, w1, w2, w3 };
#pragma unroll
    for (int m = 0; m < NMSK; ++m) {
        unsigned bit = (ww[m >> 5] >> (m & 31)) & 1u;
        unsigned long long bal = __ballot((int)bit);
        if (lane == 0) atomicAdd(&cnt[m], (int)__popcll(bal));
    }
    __syncthreads();
    if (t < NMSK) counts[s * NMSK + t] = cnt[t];
}

// ---------- stable top-k selection per mask + contrib bits + frac_kept ----------
__global__ void __launch_bounds__(SPTS) k_topk(const int* counts, unsigned* contrib, float* frac_kept) {
    int m = blockIdx.x;   // mask id
    int s = threadIdx.x;  // superpoint id
    __shared__ int cl[SPTS];
    cl[s] = counts[s * NMSK + m];
    __syncthreads();
    int c = cl[s];
    int rank = 0;
    for (int s2 = 0; s2 < SPTS; ++s2) {
        int c2 = cl[s2];
        rank += (c2 > c || (c2 == c && s2 < s)) ? 1 : 0;
    }
    bool sel = (rank < TOPK_SEL);
    float frac = (float)c / 512.0f;   // counts / (P + 1e-6) == counts / 512.0f in fp32
    frac_kept[s * NMSK + m] = sel ? frac : 0.0f;
    if (sel && frac >= 0.2f)
        atomicOr(&contrib[s * 4 + (m >> 5)], 1u << (m & 31));
}

// ---------- superpoint features (mean over P, L2-normalized) ----------
__global__ void __launch_bounds__(256) k_feats(const float* feas, float* feats) {
    int s = blockIdx.x;
    int t = threadIdx.x;        // 256 threads
    int d = t & 31, pr = t >> 5; // 8 point-groups x 32 dims
    const float* base = feas + (size_t)s * PPS * FDIM;
    float acc = 0.0f;
    for (int p = pr; p < PPS; p += 8) acc += base[p * FDIM + d];
    __shared__ float part[8][FDIM];
    part[pr][d] = acc;
    __syncthreads();
    if (t < FDIM) {
        float sum = 0.0f;
        for (int g = 0; g < 8; ++g) sum += part[g][t];
        float f = sum / 512.0f;   // / (P + 1e-6) == 512.0f in fp32
        float sq = f * f;
        for (int off = 16; off >= 1; off >>= 1) sq += __shfl_xor(sq, off);
        float nrm = sqrtf(sq);
        feats[s * FDIM + t] = f / fmaxf(nrm, 1e-12f);
    }
}

// ---------- base adjacency from rep-set min distances ----------
__global__ void __launch_bounds__(256) k_adj(const float* reps, float* out) {
    int idx = blockIdx.x * blockDim.x + threadIdx.x;
    int i = idx >> 9, j = idx & 511;
    __shared__ float ri[KFPS * 3];
    __shared__ float sqi[KFPS];
    if (threadIdx.x < KFPS * 3) ri[threadIdx.x] = reps[(size_t)i * KFPS * 3 + threadIdx.x];
    __syncthreads();
    if (threadIdx.x < KFPS) {
        float X = ri[threadIdx.x * 3], Y = ri[threadIdx.x * 3 + 1], Z = ri[threadIdx.x * 3 + 2];
        sqi[threadIdx.x] = X * X + Y * Y + Z * Z;
    }
    __syncthreads();
    float rjx[KFPS], rjy[KFPS], rjz[KFPS], sqj[KFPS];
    const float* rp = reps + (size_t)j * KFPS * 3;
#pragma unroll
    for (int b = 0; b < KFPS; ++b) {
        float X = rp[b * 3], Y = rp[b * 3 + 1], Z = rp[b * 3 + 2];
        rjx[b] = X; rjy[b] = Y; rjz[b] = Z;
        sqj[b] = X * X + Y * Y + Z * Z;
    }
    float mn = 1e30f;
#pragma unroll
    for (int a = 0; a < KFPS; ++a) {
        float ax = ri[a * 3], ay = ri[a * 3 + 1], az = ri[a * 3 + 2];
        float sa = sqi[a];
#pragma unroll
        for (int b = 0; b < KFPS; ++b) {
            float dot = ax * rjx[b] + ay * rjy[b] + az * rjz[b];
            float d2 = (sa + sqj[b]) - 2.0f * dot;   // mirror reference formula
            mn = fminf(mn, d2);
        }
    }
    float dmin = sqrtf(fmaxf(mn, 1e-12f));
    out[idx] = (dmin < 0.2f && i != j) ? expf(-dmin) : 0.0f;
}

// ---------- modulate adjacency by mask-overlap IoU and feature similarity ----------
__global__ void __launch_bounds__(256) k_mod(float* out, const unsigned* contrib, const float* feats) {
    int idx = blockIdx.x * blockDim.x + threadIdx.x;
    int i = idx >> 9, j = idx & 511;
    float a = out[idx];
    if (a <= 0.0f) return;
    uint4 c4i = *((const uint4*)(contrib + (size_t)i * 4));
    uint4 c4j = *((const uint4*)(contrib + (size_t)j * 4));
    unsigned cia[4] = { c4i.x, c4i.y, c4i.z, c4i.w };
    unsigned cja[4] = { c4j.x, c4j.y, c4j.z, c4j.w };
    int taken = 0, inter = 0, uni = 0;
#pragma unroll
    for (int w = 0; w < 4; ++w) {
        unsigned u = cia[w] | cja[w];
        unsigned both = cia[w] & cja[w];
        while (u && taken < NMASK_TOP) {
            unsigned bit = u & (~u + 1u);  // lowest set bit -> ascending index order
            uni++;
            if (both & bit) inter++;
            u ^= bit; taken++;
        }
    }
    float overlap = (float)inter / ((float)uni + 1e-6f);
    const float* fi = feats + (size_t)i * FDIM;
    const float* fj = feats + (size_t)j * FDIM;
    float dot = 0.0f;
#pragma unroll
    for (int d = 0; d < FDIM; ++d) dot += fi[d] * fj[d];
    float sim = (dot + 1.0f) / 2.0f;
    sim = fminf(fmaxf(sim, 0.0f), 1.0f);
    if (sim < 0.5f) sim = 1.0f;
    float mod = overlap * sim;
    out[idx] = fmaxf(mod, a);
}

// ---------- superpoint confidence ----------
__global__ void __launch_bounds__(256) k_conf(const float* frac_kept, const float* sam, float* out) {
    int s = blockIdx.x * blockDim.x + threadIdx.x;
    if (s >= SPTS) return;
    float sw = 0.0f, sf = 0.0f;
    for (int m = 0; m < NMSK; ++m) {
        float fk = frac_kept[s * NMSK + m];
        sw += fk * sam[m];
        sf += fk;
    }
    out[(size_t)SPTS * SPTS + s] = fmaxf(sw / (sf + 1e-6f), 0.0f);
}

extern "C" void kernel_launch(void* const* d_in, const int* in_sizes, int n_in,
                              void* d_out, int out_size, void* d_ws, size_t ws_size,
                              hipStream_t stream) {
    const float* pcds    = (const float*)d_in[0];
    // d_in[1] = spt_labels (unused: superpoints are contiguous groups of P)
    const void*  masks   = d_in[2];
    const int*   mapping = (const int*)d_in[3];
    const float* sam     = (const float*)d_in[4];
    const float* feas    = (const float*)d_in[5];
    float* out = (float*)d_out;

    char* ws = (char*)d_ws;
    size_t off = 0;
    auto take = [&](size_t bytes) -> void* {
        void* p = ws + off;
        off += (bytes + 255) & ~(size_t)255;
        return p;
    };
    int*      cfg       = (int*)take(256);
    float*    reps      = (float*)take((size_t)SPTS * KFPS * 3 * sizeof(float));
    int*      counts    = (int*)take((size_t)SPTS * NMSK * sizeof(int));
    unsigned* contrib   = (unsigned*)take((size_t)SPTS * 4 * sizeof(unsigned));
    float*    frac_kept = (float*)take((size_t)SPTS * NMSK * sizeof(float));
    float*    feats     = (float*)take((size_t)SPTS * FDIM * sizeof(float));
    unsigned* maskbits  = (unsigned*)take((size_t)HWPIX * 4 * sizeof(unsigned));
    size_t need_packed = off;
    int packed = (ws_size >= need_packed) ? 1 : 0;

    k_detect<<<1, 256, 0, stream>>>((const unsigned char*)masks, cfg);
    hipMemsetAsync(contrib, 0, (size_t)SPTS * 4 * sizeof(unsigned), stream);
    if (packed)
        k_repack_fast<<<512, 256, 0, stream>>>(masks, cfg, maskbits);
    k_fps<<<SPTS, PPS, 0, stream>>>(pcds, reps);
    k_counts<<<SPTS, PPS, 0, stream>>>(mapping, maskbits, masks, cfg, packed, counts);
    k_topk<<<NMSK, SPTS, 0, stream>>>(counts, contrib, frac_kept);
    k_feats<<<SPTS, 256, 0, stream>>>(feas, feats);
    k_adj<<<(SPTS * SPTS) / 256, 256, 0, stream>>>(reps, out);
    k_mod<<<(SPTS * SPTS) / 256, 256, 0, stream>>>(out, contrib, feats);
    k_conf<<<2, 256, 0, stream>>>(frac_kept, sam, out);
}

// Round 3
// 120.933 us; speedup vs baseline: 1.2422x; 1.0198x over previous
//
#include <hip/hip_runtime.h>
#include <cstddef>
#include <cstdint>

#define SPTS 512
#define PPS  512
#define KFPS 10
#define NMSK 128
#define HH 512
#define WW 512
#define HWPIX (HH*WW)
#define FDIM 32
#define TOPK_SEL 10
#define NMASK_TOP 5

// ---------- mask dtype handling (u8 / int32 / float32) ----------
__device__ __forceinline__ unsigned mask_val(const void* raw, long long idx, int mode) {
    if (mode == 0) return ((const unsigned char*)raw)[idx] ? 1u : 0u;
    if (mode == 1) return ((const int*)raw)[idx] ? 1u : 0u;
    return (((const float*)raw)[idx] != 0.0f) ? 1u : 0u;
}

// Detect the element layout of the bool mask array from its first 4096 bytes.
__global__ void k_detect(const unsigned char* raw, int* cfg) {
    __shared__ int any1, any23;
    if (threadIdx.x == 0) { any1 = 0; any23 = 0; }
    __syncthreads();
    int l1 = 0, l23 = 0;
    for (int i = threadIdx.x; i < 4096; i += blockDim.x) {
        unsigned char b = raw[i];
        if (b) { int r = i & 3; if (r == 1) l1 = 1; else if (r >= 2) l23 = 1; }
    }
    if (l1)  atomicOr(&any1, 1);
    if (l23) atomicOr(&any23, 1);
    __syncthreads();
    if (threadIdx.x == 0) cfg[0] = any1 ? 0 : (any23 ? 2 : 1);
}

// ---------- repack masks: maskbits[pix][0..3] = 128 bits over masks ----------
__global__ void __launch_bounds__(256) k_repack_fast(const void* raw, const int* cfg,
                                                     unsigned* maskbits) {
    int mode = cfg[0];
    int bid = blockIdx.x;
    int half  = bid & 1;      // 0: masks 0..63, 1: masks 64..127
    int ptile = bid >> 1;     // 256 tiles x 1024 pixels
    int pix0 = ptile * 1024 + threadIdx.x * 4;
    unsigned w0[4] = {0, 0, 0, 0};   // masks [half*64, half*64+32)
    unsigned w1[4] = {0, 0, 0, 0};   // masks [half*64+32, half*64+64)
    if (mode == 0) {
        const unsigned char* base = (const unsigned char*)raw + (size_t)half * 64 * HWPIX + pix0;
#pragma unroll
        for (int m = 0; m < 64; ++m) {
            unsigned v = *(const unsigned*)(base + (size_t)m * HWPIX);
            unsigned sh = m & 31;
#pragma unroll
            for (int p = 0; p < 4; ++p) {
                unsigned bit = (v >> (8 * p)) & 1u;
                if (m < 32) w0[p] |= bit << sh; else w1[p] |= bit << sh;
            }
        }
    } else {
        const unsigned* base = (const unsigned*)raw + (size_t)half * 64 * HWPIX + pix0;
#pragma unroll 16
        for (int m = 0; m < 64; ++m) {
            uint4 v = *(const uint4*)(base + (size_t)m * HWPIX);
            unsigned sh = m & 31;
            unsigned b0 = (v.x != 0u), b1 = (v.y != 0u), b2 = (v.z != 0u), b3 = (v.w != 0u);
            if (m < 32) {
                w0[0] |= b0 << sh; w0[1] |= b1 << sh; w0[2] |= b2 << sh; w0[3] |= b3 << sh;
            } else {
                w1[0] |= b0 << sh; w1[1] |= b1 << sh; w1[2] |= b2 << sh; w1[3] |= b3 << sh;
            }
        }
    }
#pragma unroll
    for (int p = 0; p < 4; ++p) {
        uint2 o; o.x = w0[p]; o.y = w1[p];
        *(uint2*)(maskbits + (size_t)(pix0 + p) * 4 + half * 2) = o;
    }
}

// ---------- FPS per superpoint; writes rep coordinates ----------
__global__ void __launch_bounds__(PPS) k_fps(const float* pcds, float* reps) {
    int s = blockIdx.x;
    int t = threadIdx.x;
    const float* base = pcds + (size_t)s * PPS * 3;
    float x = base[t * 3 + 0], y = base[t * 3 + 1], z = base[t * 3 + 2];
    float ax = base[0], ay = base[1], az = base[2];
    float dx = x - ax, dy = y - ay, dz = z - az;
    float dist = sqrtf(dx * dx + dy * dy + dz * dz);
    if (t == 0) {
        reps[((size_t)s * KFPS + 0) * 3 + 0] = ax;
        reps[((size_t)s * KFPS + 0) * 3 + 1] = ay;
        reps[((size_t)s * KFPS + 0) * 3 + 2] = az;
    }
    __shared__ float swv[8];
    __shared__ int   swi[8];
    __shared__ int   sIdx;
    for (int kk = 1; kk < KFPS; ++kk) {
        float v = dist; int idx = t;
        // wave argmax, tie -> lower index (matches jnp.argmax first-max)
        for (int off = 32; off >= 1; off >>= 1) {
            float ov = __shfl_xor(v, off);
            int   oi = __shfl_xor(idx, off);
            if (ov > v || (ov == v && oi < idx)) { v = ov; idx = oi; }
        }
        int wave = t >> 6, lane = t & 63;
        if (lane == 0) { swv[wave] = v; swi[wave] = idx; }
        __syncthreads();
        if (t == 0) {
            float bv = swv[0]; int bi = swi[0];
            for (int w = 1; w < 8; ++w)
                if (swv[w] > bv || (swv[w] == bv && swi[w] < bi)) { bv = swv[w]; bi = swi[w]; }
            sIdx = bi;
        }
        __syncthreads();
        int bi = sIdx;
        float px = base[bi * 3 + 0], py = base[bi * 3 + 1], pz = base[bi * 3 + 2];
        float ex = x - px, ey = y - py, ez = z - pz;
        float d = sqrtf(ex * ex + ey * ey + ez * ez);
        dist = fminf(dist, d);
        if (t == 0) {
            reps[((size_t)s * KFPS + kk) * 3 + 0] = px;
            reps[((size_t)s * KFPS + kk) * 3 + 1] = py;
            reps[((size_t)s * KFPS + kk) * 3 + 2] = pz;
        }
        __syncthreads();
    }
}

// ---------- per-superpoint per-mask coverage counts (+ zero contrib for k_topk) ----------
__global__ void __launch_bounds__(PPS) k_counts(const int* mapping, const unsigned* maskbits,
                                                const void* raw, const int* cfg, int packed,
                                                int* counts, unsigned* contrib) {
    int s = blockIdx.x;
    int t = threadIdx.x;
    if (t < 4) contrib[s * 4 + t] = 0u;   // zeroed here; k_topk (next dispatch) atomicOrs
    __shared__ int cnt[NMSK];
    if (t < NMSK) cnt[t] = 0;
    __syncthreads();
    int i = s * PPS + t;
    int y = mapping[i * 4 + 1]; y = min(max(y, 0), HH - 1);
    int x = mapping[i * 4 + 2]; x = min(max(x, 0), WW - 1);
    bool vis = (mapping[i * 4 + 3] == 1);
    unsigned w0 = 0, w1 = 0, w2 = 0, w3 = 0;
    if (vis) {
        if (packed) {
            uint4 v = *((const uint4*)(maskbits + (size_t)(y * WW + x) * 4));
            w0 = v.x; w1 = v.y; w2 = v.z; w3 = v.w;
        } else {
            int mode = cfg[0];
            long long pix = (long long)y * WW + x;
            for (int m = 0; m < NMSK; ++m) {
                unsigned v = mask_val(raw, (long long)m * HWPIX + pix, mode);
                if (m < 32)       w0 |= v << m;
                else if (m < 64)  w1 |= v << (m - 32);
                else if (m < 96)  w2 |= v << (m - 64);
                else              w3 |= v << (m - 96);
            }
        }
    }
    int lane = t & 63;
    unsigned ww[4] = { w0, w1, w2, w3 };
#pragma unroll
    for (int m = 0; m < NMSK; ++m) {
        unsigned bit = (ww[m >> 5] >> (m & 31)) & 1u;
        unsigned long long bal = __ballot((int)bit);
        if (lane == 0) atomicAdd(&cnt[m], (int)__popcll(bal));
    }
    __syncthreads();
    if (t < NMSK) counts[s * NMSK + t] = cnt[t];
}

// ---------- stable top-k selection per mask + contrib bits + frac_kept ----------
__global__ void __launch_bounds__(SPTS) k_topk(const int* counts, unsigned* contrib, float* frac_kept) {
    int m = blockIdx.x;   // mask id
    int s = threadIdx.x;  // superpoint id
    __shared__ int cl[SPTS];
    cl[s] = counts[s * NMSK + m];
    __syncthreads();
    int c = cl[s];
    int rank = 0;
    for (int s2 = 0; s2 < SPTS; ++s2) {
        int c2 = cl[s2];
        rank += (c2 > c || (c2 == c && s2 < s)) ? 1 : 0;
    }
    bool sel = (rank < TOPK_SEL);
    float frac = (float)c / 512.0f;   // counts / (P + 1e-6) == counts / 512.0f in fp32
    frac_kept[s * NMSK + m] = sel ? frac : 0.0f;
    if (sel && frac >= 0.2f)
        atomicOr(&contrib[s * 4 + (m >> 5)], 1u << (m & 31));
}

// ---------- superpoint features (mean over P, L2-normalized) ----------
__global__ void __launch_bounds__(256) k_feats(const float* feas, float* feats) {
    int s = blockIdx.x;
    int t = threadIdx.x;        // 256 threads
    int d = t & 31, pr = t >> 5; // 8 point-groups x 32 dims
    const float* base = feas + (size_t)s * PPS * FDIM;
    float acc = 0.0f;
    for (int p = pr; p < PPS; p += 8) acc += base[p * FDIM + d];
    __shared__ float part[8][FDIM];
    part[pr][d] = acc;
    __syncthreads();
    if (t < FDIM) {
        float sum = 0.0f;
        for (int g = 0; g < 8; ++g) sum += part[g][t];
        float f = sum / 512.0f;   // / (P + 1e-6) == 512.0f in fp32
        float sq = f * f;
        for (int off = 16; off >= 1; off >>= 1) sq += __shfl_xor(sq, off);
        float nrm = sqrtf(sq);
        feats[s * FDIM + t] = f / fmaxf(nrm, 1e-12f);
    }
}

// ---------- base adjacency from rep-set min distances ----------
__global__ void __launch_bounds__(256) k_adj(const float* reps, float* out) {
    int idx = blockIdx.x * blockDim.x + threadIdx.x;
    int i = idx >> 9, j = idx & 511;
    __shared__ float ri[KFPS * 3];
    __shared__ float sqi[KFPS];
    if (threadIdx.x < KFPS * 3) ri[threadIdx.x] = reps[(size_t)i * KFPS * 3 + threadIdx.x];
    __syncthreads();
    if (threadIdx.x < KFPS) {
        float X = ri[threadIdx.x * 3], Y = ri[threadIdx.x * 3 + 1], Z = ri[threadIdx.x * 3 + 2];
        sqi[threadIdx.x] = X * X + Y * Y + Z * Z;
    }
    __syncthreads();
    float rjx[KFPS], rjy[KFPS], rjz[KFPS], sqj[KFPS];
    const float* rp = reps + (size_t)j * KFPS * 3;
#pragma unroll
    for (int b = 0; b < KFPS; ++b) {
        float X = rp[b * 3], Y = rp[b * 3 + 1], Z = rp[b * 3 + 2];
        rjx[b] = X; rjy[b] = Y; rjz[b] = Z;
        sqj[b] = X * X + Y * Y + Z * Z;
    }
    float mn = 1e30f;
#pragma unroll
    for (int a = 0; a < KFPS; ++a) {
        float ax = ri[a * 3], ay = ri[a * 3 + 1], az = ri[a * 3 + 2];
        float sa = sqi[a];
#pragma unroll
        for (int b = 0; b < KFPS; ++b) {
            float dot = ax * rjx[b] + ay * rjy[b] + az * rjz[b];
            float d2 = (sa + sqj[b]) - 2.0f * dot;   // mirror reference formula
            mn = fminf(mn, d2);
        }
    }
    float dmin = sqrtf(fmaxf(mn, 1e-12f));
    out[idx] = (dmin < 0.2f && i != j) ? expf(-dmin) : 0.0f;
}

// ---------- modulate adjacency by mask-overlap IoU and feature similarity ----------
__global__ void __launch_bounds__(256) k_mod(float* out, const unsigned* contrib, const float* feats) {
    int idx = blockIdx.x * blockDim.x + threadIdx.x;
    int i = idx >> 9, j = idx & 511;
    float a = out[idx];
    if (a <= 0.0f) return;
    uint4 c4i = *((const uint4*)(contrib + (size_t)i * 4));
    uint4 c4j = *((const uint4*)(contrib + (size_t)j * 4));
    unsigned cia[4] = { c4i.x, c4i.y, c4i.z, c4i.w };
    unsigned cja[4] = { c4j.x, c4j.y, c4j.z, c4j.w };
    int taken = 0, inter = 0, uni = 0;
#pragma unroll
    for (int w = 0; w < 4; ++w) {
        unsigned u = cia[w] | cja[w];
        unsigned both = cia[w] & cja[w];
        while (u && taken < NMASK_TOP) {
            unsigned bit = u & (~u + 1u);  // lowest set bit -> ascending index order
            uni++;
            if (both & bit) inter++;
            u ^= bit; taken++;
        }
    }
    float overlap = (float)inter / ((float)uni + 1e-6f);
    const float* fi = feats + (size_t)i * FDIM;
    const float* fj = feats + (size_t)j * FDIM;
    float dot = 0.0f;
#pragma unroll
    for (int d = 0; d < FDIM; ++d) dot += fi[d] * fj[d];
    float sim = (dot + 1.0f) / 2.0f;
    sim = fminf(fmaxf(sim, 0.0f), 1.0f);
    if (sim < 0.5f) sim = 1.0f;
    float mod = overlap * sim;
    out[idx] = fmaxf(mod, a);
}

// ---------- superpoint confidence ----------
__global__ void __launch_bounds__(256) k_conf(const float* frac_kept, const float* sam, float* out) {
    int s = blockIdx.x * blockDim.x + threadIdx.x;
    if (s >= SPTS) return;
    float sw = 0.0f, sf = 0.0f;
    for (int m = 0; m < NMSK; ++m) {
        float fk = frac_kept[s * NMSK + m];
        sw += fk * sam[m];
        sf += fk;
    }
    out[(size_t)SPTS * SPTS + s] = fmaxf(sw / (sf + 1e-6f), 0.0f);
}

extern "C" void kernel_launch(void* const* d_in, const int* in_sizes, int n_in,
                              void* d_out, int out_size, void* d_ws, size_t ws_size,
                              hipStream_t stream) {
    const float* pcds    = (const float*)d_in[0];
    // d_in[1] = spt_labels (unused: superpoints are contiguous groups of P)
    const void*  masks   = d_in[2];
    const int*   mapping = (const int*)d_in[3];
    const float* sam     = (const float*)d_in[4];
    const float* feas    = (const float*)d_in[5];
    float* out = (float*)d_out;

    char* ws = (char*)d_ws;
    size_t off = 0;
    auto take = [&](size_t bytes) -> void* {
        void* p = ws + off;
        off += (bytes + 255) & ~(size_t)255;
        return p;
    };
    int*      cfg       = (int*)take(256);
    float*    reps      = (float*)take((size_t)SPTS * KFPS * 3 * sizeof(float));
    int*      counts    = (int*)take((size_t)SPTS * NMSK * sizeof(int));
    unsigned* contrib   = (unsigned*)take((size_t)SPTS * 4 * sizeof(unsigned));
    float*    frac_kept = (float*)take((size_t)SPTS * NMSK * sizeof(float));
    float*    feats     = (float*)take((size_t)SPTS * FDIM * sizeof(float));
    unsigned* maskbits  = (unsigned*)take((size_t)HWPIX * 4 * sizeof(unsigned));
    size_t need_packed = off;
    int packed = (ws_size >= need_packed) ? 1 : 0;

    k_detect<<<1, 256, 0, stream>>>((const unsigned char*)masks, cfg);
    if (packed)
        k_repack_fast<<<512, 256, 0, stream>>>(masks, cfg, maskbits);
    k_fps<<<SPTS, PPS, 0, stream>>>(pcds, reps);
    k_counts<<<SPTS, PPS, 0, stream>>>(mapping, maskbits, masks, cfg, packed, counts, contrib);
    k_topk<<<NMSK, SPTS, 0, stream>>>(counts, contrib, frac_kept);
    k_feats<<<SPTS, 256, 0, stream>>>(feas, feats);
    k_adj<<<(SPTS * SPTS) / 256, 256, 0, stream>>>(reps, out);
    k_mod<<<(SPTS * SPTS) / 256, 256, 0, stream>>>(out, contrib, feats);
    k_conf<<<2, 256, 0, stream>>>(frac_kept, sam, out);
}

// Round 4
// 98.069 us; speedup vs baseline: 1.5318x; 1.2331x over previous
//
#include <hip/hip_runtime.h>
#include <cstddef>
#include <cstdint>

#define SPTS 512
#define PPS  512
#define KFPS 10
#define NMSK 128
#define HH 512
#define WW 512
#define HWPIX (HH*WW)
#define FDIM 32
#define TOPK_SEL 10
#define NMASK_TOP 5

// ---------- mask dtype handling (u8 / int32 / float32) ----------
__device__ __forceinline__ unsigned mask_val(const void* raw, long long idx, int mode) {
    if (mode == 0) return ((const unsigned char*)raw)[idx] ? 1u : 0u;
    if (mode == 1) return ((const int*)raw)[idx] ? 1u : 0u;
    return (((const float*)raw)[idx] != 0.0f) ? 1u : 0u;
}

// In-block mask dtype detection from the first 4096 bytes (L2-hot after block 0).
// u8 bool: nonzero bytes at offsets %4==1. f32 0/1: nonzero at %4∈{2,3}. int32: %4==0 only.
__device__ __forceinline__ int detect_mode(const void* raw) {
    __shared__ int s_any1, s_any23;
    if (threadIdx.x == 0) { s_any1 = 0; s_any23 = 0; }
    __syncthreads();
    if (threadIdx.x < 256) {
        uint4 w = ((const uint4*)raw)[threadIdx.x];
        unsigned a = w.x | w.y | w.z | w.w;            // any bits
        unsigned b1  = (w.x >> 8 | w.y >> 8 | w.z >> 8 | w.w >> 8) & 0xFFu;
        unsigned b23 = ((w.x >> 16) | (w.y >> 16) | (w.z >> 16) | (w.w >> 16)) & 0xFFFFu;
        (void)a;
        if (b1)  atomicOr(&s_any1, 1);
        if (b23) atomicOr(&s_any23, 1);
    }
    __syncthreads();
    return s_any1 ? 0 : (s_any23 ? 2 : 1);
}

// ---------- repack masks: maskbits[pix][0..3] = 128 bits over masks ----------
__global__ void __launch_bounds__(256) k_repack_fast(const void* raw, unsigned* maskbits) {
    int mode = detect_mode(raw);
    int bid = blockIdx.x;
    int half  = bid & 1;      // 0: masks 0..63, 1: masks 64..127
    int ptile = bid >> 1;     // 256 tiles x 1024 pixels
    int pix0 = ptile * 1024 + threadIdx.x * 4;
    unsigned w0[4] = {0, 0, 0, 0};   // masks [half*64, half*64+32)
    unsigned w1[4] = {0, 0, 0, 0};   // masks [half*64+32, half*64+64)
    if (mode == 0) {
        const unsigned char* base = (const unsigned char*)raw + (size_t)half * 64 * HWPIX + pix0;
#pragma unroll
        for (int m = 0; m < 64; ++m) {
            unsigned v = *(const unsigned*)(base + (size_t)m * HWPIX);
            unsigned sh = m & 31;
#pragma unroll
            for (int p = 0; p < 4; ++p) {
                unsigned bit = (v >> (8 * p)) & 1u;
                if (m < 32) w0[p] |= bit << sh; else w1[p] |= bit << sh;
            }
        }
    } else {
        const unsigned* base = (const unsigned*)raw + (size_t)half * 64 * HWPIX + pix0;
#pragma unroll 16
        for (int m = 0; m < 64; ++m) {
            uint4 v = *(const uint4*)(base + (size_t)m * HWPIX);
            unsigned sh = m & 31;
            unsigned b0 = (v.x != 0u), b1 = (v.y != 0u), b2 = (v.z != 0u), b3 = (v.w != 0u);
            if (m < 32) {
                w0[0] |= b0 << sh; w0[1] |= b1 << sh; w0[2] |= b2 << sh; w0[3] |= b3 << sh;
            } else {
                w1[0] |= b0 << sh; w1[1] |= b1 << sh; w1[2] |= b2 << sh; w1[3] |= b3 << sh;
            }
        }
    }
#pragma unroll
    for (int p = 0; p < 4; ++p) {
        uint2 o; o.x = w0[p]; o.y = w1[p];
        *(uint2*)(maskbits + (size_t)(pix0 + p) * 4 + half * 2) = o;
    }
}

// ---------- wave-level FPS (no block barriers) + fused superpoint features ----------
// 1 wave per superpoint, 8 points per lane (global point p = lane + 64*k).
__global__ void __launch_bounds__(256) k_fps_feats(const float* pcds, const float* feas,
                                                   float* reps, float* feats) {
    int lane = threadIdx.x & 63;
    int wv   = threadIdx.x >> 6;
    int s    = blockIdx.x * 4 + wv;

    const float* base = pcds + (size_t)s * PPS * 3;
    float px_[8], py_[8], pz_[8];
#pragma unroll
    for (int k = 0; k < 8; ++k) {
        int p = lane + 64 * k;
        px_[k] = base[p * 3 + 0];
        py_[k] = base[p * 3 + 1];
        pz_[k] = base[p * 3 + 2];
    }
    // first rep = point 0 (lane 0, slot 0)
    float ax = __shfl(px_[0], 0), ay = __shfl(py_[0], 0), az = __shfl(pz_[0], 0);
    float dist[8];
#pragma unroll
    for (int k = 0; k < 8; ++k) {
        float dx = px_[k] - ax, dy = py_[k] - ay, dz = pz_[k] - az;
        dist[k] = sqrtf(dx * dx + dy * dy + dz * dz);
    }
    if (lane == 0) {
        reps[((size_t)s * KFPS + 0) * 3 + 0] = ax;
        reps[((size_t)s * KFPS + 0) * 3 + 1] = ay;
        reps[((size_t)s * KFPS + 0) * 3 + 2] = az;
    }
    for (int kk = 1; kk < KFPS; ++kk) {
        // local argmax over 8 (ascending k => ascending global idx; strict > keeps first)
        float bv = dist[0]; int bk = 0;
#pragma unroll
        for (int k = 1; k < 8; ++k)
            if (dist[k] > bv) { bv = dist[k]; bk = k; }
        float v = bv; int pidx = lane + 64 * bk;
        // wave argmax; tie -> lower global point index (matches jnp.argmax)
#pragma unroll
        for (int off = 1; off < 64; off <<= 1) {
            float ov = __shfl_xor(v, off);
            int   op = __shfl_xor(pidx, off);
            if (ov > v || (ov == v && op < pidx)) { v = ov; pidx = op; }
        }
        int owner = pidx & 63, slot = pidx >> 6;
        float sx = px_[0], sy = py_[0], sz = pz_[0];
#pragma unroll
        for (int j = 1; j < 8; ++j)
            if (slot == j) { sx = px_[j]; sy = py_[j]; sz = pz_[j]; }
        sx = __shfl(sx, owner); sy = __shfl(sy, owner); sz = __shfl(sz, owner);
        if (lane == 0) {
            reps[((size_t)s * KFPS + kk) * 3 + 0] = sx;
            reps[((size_t)s * KFPS + kk) * 3 + 1] = sy;
            reps[((size_t)s * KFPS + kk) * 3 + 2] = sz;
        }
#pragma unroll
        for (int k = 0; k < 8; ++k) {
            float dx = px_[k] - sx, dy = py_[k] - sy, dz = pz_[k] - sz;
            float d = sqrtf(dx * dx + dy * dy + dz * dz);
            dist[k] = fminf(dist[k], d);
        }
    }

    // ---- features: mean over P, L2-normalized. lane = half*32 + d ----
    int d = lane & 31, half = lane >> 5;
    const float* fb = feas + (size_t)s * PPS * FDIM;
    float acc = 0.0f;
#pragma unroll 8
    for (int p = half; p < PPS; p += 2) acc += fb[p * FDIM + d];
    acc += __shfl_xor(acc, 32);           // both halves -> full sum (bitwise equal)
    float f = acc / 512.0f;               // /(P+1e-6) == /512.0f in fp32
    float sq = f * f;
#pragma unroll
    for (int off = 16; off >= 1; off >>= 1) sq += __shfl_xor(sq, off);
    float nrm = sqrtf(sq);
    if (lane < 32) feats[s * FDIM + d] = f / fmaxf(nrm, 1e-12f);
}

// ---------- per-superpoint per-mask coverage counts (+ zero contrib for k_topk) ----------
__global__ void __launch_bounds__(PPS) k_counts(const int* mapping, const unsigned* maskbits,
                                                const void* raw, int packed,
                                                int* counts, unsigned* contrib) {
    int s = blockIdx.x;
    int t = threadIdx.x;
    if (t < 4) contrib[s * 4 + t] = 0u;   // zeroed here; k_topk (later dispatch) atomicOrs
    __shared__ int cnt[NMSK];
    if (t < NMSK) cnt[t] = 0;
    int mode = 0;
    if (!packed) mode = detect_mode(raw);   // has its own __syncthreads
    __syncthreads();
    int i = s * PPS + t;
    int y = mapping[i * 4 + 1]; y = min(max(y, 0), HH - 1);
    int x = mapping[i * 4 + 2]; x = min(max(x, 0), WW - 1);
    bool vis = (mapping[i * 4 + 3] == 1);
    unsigned w0 = 0, w1 = 0, w2 = 0, w3 = 0;
    if (vis) {
        if (packed) {
            uint4 v = *((const uint4*)(maskbits + (size_t)(y * WW + x) * 4));
            w0 = v.x; w1 = v.y; w2 = v.z; w3 = v.w;
        } else {
            long long pix = (long long)y * WW + x;
            for (int m = 0; m < NMSK; ++m) {
                unsigned v = mask_val(raw, (long long)m * HWPIX + pix, mode);
                if (m < 32)       w0 |= v << m;
                else if (m < 64)  w1 |= v << (m - 32);
                else if (m < 96)  w2 |= v << (m - 64);
                else              w3 |= v << (m - 96);
            }
        }
    }
    int lane = t & 63;
    unsigned ww[4] = { w0, w1, w2, w3 };
#pragma unroll
    for (int m = 0; m < NMSK; ++m) {
        unsigned bit = (ww[m >> 5] >> (m & 31)) & 1u;
        unsigned long long bal = __ballot((int)bit);
        if (lane == 0) atomicAdd(&cnt[m], (int)__popcll(bal));
    }
    __syncthreads();
    if (t < NMSK) counts[s * NMSK + t] = cnt[t];
}

// ---------- stable top-k selection per mask + contrib bits + frac_kept ----------
__global__ void __launch_bounds__(SPTS) k_topk(const int* counts, unsigned* contrib, float* frac_kept) {
    int m = blockIdx.x;   // mask id
    int s = threadIdx.x;  // superpoint id
    __shared__ int cl[SPTS];
    cl[s] = counts[s * NMSK + m];
    __syncthreads();
    int c = cl[s];
    int rank = 0;
    for (int s2 = 0; s2 < SPTS; ++s2) {
        int c2 = cl[s2];
        rank += (c2 > c || (c2 == c && s2 < s)) ? 1 : 0;
    }
    bool sel = (rank < TOPK_SEL);
    float frac = (float)c / 512.0f;   // counts / (P + 1e-6) == counts / 512.0f in fp32
    frac_kept[s * NMSK + m] = sel ? frac : 0.0f;
    if (sel && frac >= 0.2f)
        atomicOr(&contrib[s * 4 + (m >> 5)], 1u << (m & 31));
}

// ---------- fused: base adjacency + IoU/sim modulation + confidence ----------
__global__ void __launch_bounds__(256) k_adjmod(const float* reps, const unsigned* contrib,
                                                const float* feats, const float* frac_kept,
                                                const float* sam, float* out) {
    if (blockIdx.x >= (SPTS * SPTS) / 256) {
        // confidence blocks
        int s = (blockIdx.x - (SPTS * SPTS) / 256) * 256 + threadIdx.x;
        if (s < SPTS) {
            float sw = 0.0f, sf = 0.0f;
            for (int m = 0; m < NMSK; ++m) {
                float fk = frac_kept[s * NMSK + m];
                sw += fk * sam[m];
                sf += fk;
            }
            out[(size_t)SPTS * SPTS + s] = fmaxf(sw / (sf + 1e-6f), 0.0f);
        }
        return;
    }
    int idx = blockIdx.x * blockDim.x + threadIdx.x;
    int i = idx >> 9, j = idx & 511;
    __shared__ float ri[KFPS * 3];
    __shared__ float sqi[KFPS];
    if (threadIdx.x < KFPS * 3) ri[threadIdx.x] = reps[(size_t)i * KFPS * 3 + threadIdx.x];
    __syncthreads();
    if (threadIdx.x < KFPS) {
        float X = ri[threadIdx.x * 3], Y = ri[threadIdx.x * 3 + 1], Z = ri[threadIdx.x * 3 + 2];
        sqi[threadIdx.x] = X * X + Y * Y + Z * Z;
    }
    __syncthreads();
    float rjx[KFPS], rjy[KFPS], rjz[KFPS], sqj[KFPS];
    const float* rp = reps + (size_t)j * KFPS * 3;
#pragma unroll
    for (int b = 0; b < KFPS; ++b) {
        float X = rp[b * 3], Y = rp[b * 3 + 1], Z = rp[b * 3 + 2];
        rjx[b] = X; rjy[b] = Y; rjz[b] = Z;
        sqj[b] = X * X + Y * Y + Z * Z;
    }
    float mn = 1e30f;
#pragma unroll
    for (int a = 0; a < KFPS; ++a) {
        float ax = ri[a * 3], ay = ri[a * 3 + 1], az = ri[a * 3 + 2];
        float sa = sqi[a];
#pragma unroll
        for (int b = 0; b < KFPS; ++b) {
            float dot = ax * rjx[b] + ay * rjy[b] + az * rjz[b];
            float d2 = (sa + sqj[b]) - 2.0f * dot;   // mirror reference formula
            mn = fminf(mn, d2);
        }
    }
    float dmin = sqrtf(fmaxf(mn, 1e-12f));
    float a = (dmin < 0.2f && i != j) ? expf(-dmin) : 0.0f;
    if (a > 0.0f) {
        uint4 c4i = *((const uint4*)(contrib + (size_t)i * 4));
        uint4 c4j = *((const uint4*)(contrib + (size_t)j * 4));
        unsigned cia[4] = { c4i.x, c4i.y, c4i.z, c4i.w };
        unsigned cja[4] = { c4j.x, c4j.y, c4j.z, c4j.w };
        int taken = 0, inter = 0, uni = 0;
#pragma unroll
        for (int w = 0; w < 4; ++w) {
            unsigned u = cia[w] | cja[w];
            unsigned both = cia[w] & cja[w];
            while (u && taken < NMASK_TOP) {
                unsigned bit = u & (~u + 1u);  // lowest set bit -> ascending index order
                uni++;
                if (both & bit) inter++;
                u ^= bit; taken++;
            }
        }
        float overlap = (float)inter / ((float)uni + 1e-6f);
        const float* fi = feats + (size_t)i * FDIM;
        const float* fj = feats + (size_t)j * FDIM;
        float dot = 0.0f;
#pragma unroll
        for (int d = 0; d < FDIM; ++d) dot += fi[d] * fj[d];
        float sim = (dot + 1.0f) / 2.0f;
        sim = fminf(fmaxf(sim, 0.0f), 1.0f);
        if (sim < 0.5f) sim = 1.0f;
        a = fmaxf(overlap * sim, a);
    }
    out[idx] = a;
}

extern "C" void kernel_launch(void* const* d_in, const int* in_sizes, int n_in,
                              void* d_out, int out_size, void* d_ws, size_t ws_size,
                              hipStream_t stream) {
    const float* pcds    = (const float*)d_in[0];
    // d_in[1] = spt_labels (unused: superpoints are contiguous groups of P)
    const void*  masks   = d_in[2];
    const int*   mapping = (const int*)d_in[3];
    const float* sam     = (const float*)d_in[4];
    const float* feas    = (const float*)d_in[5];
    float* out = (float*)d_out;

    char* ws = (char*)d_ws;
    size_t off = 0;
    auto take = [&](size_t bytes) -> void* {
        void* p = ws + off;
        off += (bytes + 255) & ~(size_t)255;
        return p;
    };
    float*    reps      = (float*)take((size_t)SPTS * KFPS * 3 * sizeof(float));
    int*      counts    = (int*)take((size_t)SPTS * NMSK * sizeof(int));
    unsigned* contrib   = (unsigned*)take((size_t)SPTS * 4 * sizeof(unsigned));
    float*    frac_kept = (float*)take((size_t)SPTS * NMSK * sizeof(float));
    float*    feats     = (float*)take((size_t)SPTS * FDIM * sizeof(float));
    unsigned* maskbits  = (unsigned*)take((size_t)HWPIX * 4 * sizeof(unsigned));
    size_t need_packed = off;
    int packed = (ws_size >= need_packed) ? 1 : 0;

    if (packed)
        k_repack_fast<<<512, 256, 0, stream>>>(masks, maskbits);
    k_fps_feats<<<SPTS / 4, 256, 0, stream>>>(pcds, feas, reps, feats);
    k_counts<<<SPTS, PPS, 0, stream>>>(mapping, maskbits, masks, packed, counts, contrib);
    k_topk<<<NMSK, SPTS, 0, stream>>>(counts, contrib, frac_kept);
    k_adjmod<<<(SPTS * SPTS) / 256 + 2, 256, 0, stream>>>(reps, contrib, feats, frac_kept, sam, out);
}

// Round 5
// 78.663 us; speedup vs baseline: 1.9097x; 1.2467x over previous
//
#include <hip/hip_runtime.h>
#include <cstddef>
#include <cstdint>

#define SPTS 512
#define PPS  512
#define KFPS 10
#define NMSK 128
#define HH 512
#define WW 512
#define HWPIX (HH*WW)
#define FDIM 32
#define TOPK_SEL 10
#define NMASK_TOP 5

// ---------- mask dtype handling (u8 / int32 / float32) ----------
__device__ __forceinline__ unsigned mask_val(const void* raw, long long idx, int mode) {
    if (mode == 0) return ((const unsigned char*)raw)[idx] ? 1u : 0u;
    if (mode == 1) return ((const int*)raw)[idx] ? 1u : 0u;
    return (((const float*)raw)[idx] != 0.0f) ? 1u : 0u;
}

// In-block mask dtype detection from the first 4096 bytes (L2-hot after block 0).
// u8 bool: nonzero bytes at offsets %4==1. f32 0/1: nonzero at %4∈{2,3}. int32: %4==0 only.
__device__ __forceinline__ int detect_mode(const void* raw) {
    __shared__ int s_any1, s_any23;
    if (threadIdx.x == 0) { s_any1 = 0; s_any23 = 0; }
    __syncthreads();
    if (threadIdx.x < 256) {
        uint4 w = ((const uint4*)raw)[threadIdx.x];
        unsigned b1  = (w.x >> 8 | w.y >> 8 | w.z >> 8 | w.w >> 8) & 0xFFu;
        unsigned b23 = ((w.x >> 16) | (w.y >> 16) | (w.z >> 16) | (w.w >> 16)) & 0xFFFFu;
        if (b1)  atomicOr(&s_any1, 1);
        if (b23) atomicOr(&s_any23, 1);
    }
    __syncthreads();
    return s_any1 ? 0 : (s_any23 ? 2 : 1);
}

// ---------- fused: repack masks (blocks 0..511) + wave-level FPS (blocks 512..639) ----------
// repack: maskbits[pix][0..3] = 128 bits over masks, 4 pixels/thread, 64-mask half/block.
// FPS: 1 wave per superpoint, 8 points/lane, shuffle-only argmax (no block barriers).
__global__ void __launch_bounds__(256) k_repack_fps(const void* raw, unsigned* maskbits,
                                                    const float* pcds, float* reps) {
    int bid = blockIdx.x;
    if (bid < 512) {
        int mode = detect_mode(raw);
        int half  = bid & 1;      // 0: masks 0..63, 1: masks 64..127
        int ptile = bid >> 1;     // 256 tiles x 1024 pixels
        int pix0 = ptile * 1024 + threadIdx.x * 4;
        unsigned w0[4] = {0, 0, 0, 0};   // masks [half*64, half*64+32)
        unsigned w1[4] = {0, 0, 0, 0};   // masks [half*64+32, half*64+64)
        if (mode == 0) {
            const unsigned char* base = (const unsigned char*)raw + (size_t)half * 64 * HWPIX + pix0;
#pragma unroll
            for (int m = 0; m < 64; ++m) {
                unsigned v = *(const unsigned*)(base + (size_t)m * HWPIX);
                unsigned sh = m & 31;
#pragma unroll
                for (int p = 0; p < 4; ++p) {
                    unsigned bit = (v >> (8 * p)) & 1u;
                    if (m < 32) w0[p] |= bit << sh; else w1[p] |= bit << sh;
                }
            }
        } else {
            const unsigned* base = (const unsigned*)raw + (size_t)half * 64 * HWPIX + pix0;
#pragma unroll 16
            for (int m = 0; m < 64; ++m) {
                uint4 v = *(const uint4*)(base + (size_t)m * HWPIX);
                unsigned sh = m & 31;
                unsigned b0 = (v.x != 0u), b1 = (v.y != 0u), b2 = (v.z != 0u), b3 = (v.w != 0u);
                if (m < 32) {
                    w0[0] |= b0 << sh; w0[1] |= b1 << sh; w0[2] |= b2 << sh; w0[3] |= b3 << sh;
                } else {
                    w1[0] |= b0 << sh; w1[1] |= b1 << sh; w1[2] |= b2 << sh; w1[3] |= b3 << sh;
                }
            }
        }
#pragma unroll
        for (int p = 0; p < 4; ++p) {
            uint2 o; o.x = w0[p]; o.y = w1[p];
            *(uint2*)(maskbits + (size_t)(pix0 + p) * 4 + half * 2) = o;
        }
        return;
    }
    // ---- FPS role ----
    int lane = threadIdx.x & 63;
    int wv   = threadIdx.x >> 6;
    int s    = (bid - 512) * 4 + wv;
    const float* base = pcds + (size_t)s * PPS * 3;
    float px_[8], py_[8], pz_[8];
#pragma unroll
    for (int k = 0; k < 8; ++k) {
        int p = lane + 64 * k;
        px_[k] = base[p * 3 + 0];
        py_[k] = base[p * 3 + 1];
        pz_[k] = base[p * 3 + 2];
    }
    float ax = __shfl(px_[0], 0), ay = __shfl(py_[0], 0), az = __shfl(pz_[0], 0);
    float dist[8];
#pragma unroll
    for (int k = 0; k < 8; ++k) {
        float dx = px_[k] - ax, dy = py_[k] - ay, dz = pz_[k] - az;
        dist[k] = sqrtf(dx * dx + dy * dy + dz * dz);
    }
    if (lane == 0) {
        reps[((size_t)s * KFPS + 0) * 3 + 0] = ax;
        reps[((size_t)s * KFPS + 0) * 3 + 1] = ay;
        reps[((size_t)s * KFPS + 0) * 3 + 2] = az;
    }
    for (int kk = 1; kk < KFPS; ++kk) {
        float bv = dist[0]; int bk = 0;
#pragma unroll
        for (int k = 1; k < 8; ++k)
            if (dist[k] > bv) { bv = dist[k]; bk = k; }
        float v = bv; int pidx = lane + 64 * bk;
        // wave argmax; tie -> lower global point index (matches jnp.argmax)
#pragma unroll
        for (int off = 1; off < 64; off <<= 1) {
            float ov = __shfl_xor(v, off);
            int   op = __shfl_xor(pidx, off);
            if (ov > v || (ov == v && op < pidx)) { v = ov; pidx = op; }
        }
        int owner = pidx & 63, slot = pidx >> 6;
        float sx = px_[0], sy = py_[0], sz = pz_[0];
#pragma unroll
        for (int j = 1; j < 8; ++j)
            if (slot == j) { sx = px_[j]; sy = py_[j]; sz = pz_[j]; }
        sx = __shfl(sx, owner); sy = __shfl(sy, owner); sz = __shfl(sz, owner);
        if (lane == 0) {
            reps[((size_t)s * KFPS + kk) * 3 + 0] = sx;
            reps[((size_t)s * KFPS + kk) * 3 + 1] = sy;
            reps[((size_t)s * KFPS + kk) * 3 + 2] = sz;
        }
#pragma unroll
        for (int k = 0; k < 8; ++k) {
            float dx = px_[k] - sx, dy = py_[k] - sy, dz = pz_[k] - sz;
            float d = sqrtf(dx * dx + dy * dy + dz * dz);
            dist[k] = fminf(dist[k], d);
        }
    }
}

// ---------- counts + feats fused (512 blocks x 512 threads, full machine) ----------
__global__ void __launch_bounds__(PPS) k_counts_feats(const int* mapping, const unsigned* maskbits,
                                                      const void* raw, int packed,
                                                      const float* feas,
                                                      int* counts, unsigned* contrib, float* feats) {
    int s = blockIdx.x;
    int t = threadIdx.x;
    if (t < 4) contrib[s * 4 + t] = 0u;   // zeroed here; k_topk (later dispatch) atomicOrs
    __shared__ int cnt[NMSK];
    __shared__ float fpart[16][FDIM];
    if (t < NMSK) cnt[t] = 0;
    int mode = 0;
    if (!packed) mode = detect_mode(raw);   // has its own __syncthreads
    __syncthreads();
    int i = s * PPS + t;
    int4 mp = ((const int4*)mapping)[i];
    int y = min(max(mp.y, 0), HH - 1);
    int x = min(max(mp.z, 0), WW - 1);
    bool vis = (mp.w == 1);
    unsigned w0 = 0, w1 = 0, w2 = 0, w3 = 0;
    if (vis) {
        if (packed) {
            uint4 v = *((const uint4*)(maskbits + (size_t)(y * WW + x) * 4));
            w0 = v.x; w1 = v.y; w2 = v.z; w3 = v.w;
        } else {
            long long pix = (long long)y * WW + x;
            for (int m = 0; m < NMSK; ++m) {
                unsigned v = mask_val(raw, (long long)m * HWPIX + pix, mode);
                if (m < 32)       w0 |= v << m;
                else if (m < 64)  w1 |= v << (m - 32);
                else if (m < 96)  w2 |= v << (m - 64);
                else              w3 |= v << (m - 96);
            }
        }
    }
    int lane = t & 63;
    unsigned ww[4] = { w0, w1, w2, w3 };
#pragma unroll
    for (int m = 0; m < NMSK; ++m) {
        unsigned bit = (ww[m >> 5] >> (m & 31)) & 1u;
        unsigned long long bal = __ballot((int)bit);
        if (lane == 0) atomicAdd(&cnt[m], (int)__popcll(bal));
    }
    // ---- feats: dim d = t&31, point-group g = t>>5 (16 groups x 32 points) ----
    {
        int g = t >> 5, d = t & 31;
        const float* fb = feas + (size_t)s * PPS * FDIM;
        float acc = 0.0f;
#pragma unroll 8
        for (int it = 0; it < 32; ++it) acc += fb[(g + 16 * it) * FDIM + d];
        fpart[g][d] = acc;
    }
    __syncthreads();
    if (t < NMSK) counts[s * NMSK + t] = cnt[t];
    if (t < FDIM) {
        float sum = 0.0f;
#pragma unroll
        for (int q = 0; q < 16; ++q) sum += fpart[q][t];
        float f = sum / 512.0f;   // /(P+1e-6) == /512.0f in fp32
        float sq = f * f;
#pragma unroll
        for (int off = 16; off >= 1; off >>= 1) sq += __shfl_xor(sq, off);
        feats[s * FDIM + t] = f / fmaxf(sqrtf(sq), 1e-12f);
    }
}

// ---------- stable top-k selection per mask + contrib bits + frac_kept ----------
__global__ void __launch_bounds__(SPTS) k_topk(const int* counts, unsigned* contrib, float* frac_kept) {
    int m = blockIdx.x;   // mask id
    int s = threadIdx.x;  // superpoint id
    __shared__ int cl[SPTS];
    cl[s] = counts[s * NMSK + m];
    __syncthreads();
    int c = cl[s];
    int rank = 0;
    for (int s2 = 0; s2 < SPTS; ++s2) {
        int c2 = cl[s2];
        rank += (c2 > c || (c2 == c && s2 < s)) ? 1 : 0;
    }
    bool sel = (rank < TOPK_SEL);
    float frac = (float)c / 512.0f;   // counts / (P + 1e-6) == counts / 512.0f in fp32
    frac_kept[s * NMSK + m] = sel ? frac : 0.0f;
    if (sel && frac >= 0.2f)
        atomicOr(&contrib[s * 4 + (m >> 5)], 1u << (m & 31));
}

// ---------- fused: base adjacency + IoU/sim modulation + confidence ----------
__global__ void __launch_bounds__(256) k_adjmod(const float* reps, const unsigned* contrib,
                                                const float* feats, const float* frac_kept,
                                                const float* sam, float* out) {
    if (blockIdx.x >= (SPTS * SPTS) / 256) {
        // confidence blocks
        int s = (blockIdx.x - (SPTS * SPTS) / 256) * 256 + threadIdx.x;
        if (s < SPTS) {
            float sw = 0.0f, sf = 0.0f;
            for (int m = 0; m < NMSK; ++m) {
                float fk = frac_kept[s * NMSK + m];
                sw += fk * sam[m];
                sf += fk;
            }
            out[(size_t)SPTS * SPTS + s] = fmaxf(sw / (sf + 1e-6f), 0.0f);
        }
        return;
    }
    int idx = blockIdx.x * blockDim.x + threadIdx.x;
    int i = idx >> 9, j = idx & 511;
    __shared__ float ri[KFPS * 3];
    __shared__ float sqi[KFPS];
    if (threadIdx.x < KFPS * 3) ri[threadIdx.x] = reps[(size_t)i * KFPS * 3 + threadIdx.x];
    __syncthreads();
    if (threadIdx.x < KFPS) {
        float X = ri[threadIdx.x * 3], Y = ri[threadIdx.x * 3 + 1], Z = ri[threadIdx.x * 3 + 2];
        sqi[threadIdx.x] = X * X + Y * Y + Z * Z;
    }
    __syncthreads();
    float rjx[KFPS], rjy[KFPS], rjz[KFPS], sqj[KFPS];
    const float* rp = reps + (size_t)j * KFPS * 3;
#pragma unroll
    for (int b = 0; b < KFPS; ++b) {
        float X = rp[b * 3], Y = rp[b * 3 + 1], Z = rp[b * 3 + 2];
        rjx[b] = X; rjy[b] = Y; rjz[b] = Z;
        sqj[b] = X * X + Y * Y + Z * Z;
    }
    float mn = 1e30f;
#pragma unroll
    for (int a = 0; a < KFPS; ++a) {
        float ax = ri[a * 3], ay = ri[a * 3 + 1], az = ri[a * 3 + 2];
        float sa = sqi[a];
#pragma unroll
        for (int b = 0; b < KFPS; ++b) {
            float dot = ax * rjx[b] + ay * rjy[b] + az * rjz[b];
            float d2 = (sa + sqj[b]) - 2.0f * dot;   // mirror reference formula
            mn = fminf(mn, d2);
        }
    }
    float dmin = sqrtf(fmaxf(mn, 1e-12f));
    float a = (dmin < 0.2f && i != j) ? expf(-dmin) : 0.0f;
    if (a > 0.0f) {
        uint4 c4i = *((const uint4*)(contrib + (size_t)i * 4));
        uint4 c4j = *((const uint4*)(contrib + (size_t)j * 4));
        unsigned cia[4] = { c4i.x, c4i.y, c4i.z, c4i.w };
        unsigned cja[4] = { c4j.x, c4j.y, c4j.z, c4j.w };
        int taken = 0, inter = 0, uni = 0;
#pragma unroll
        for (int w = 0; w < 4; ++w) {
            unsigned u = cia[w] | cja[w];
            unsigned both = cia[w] & cja[w];
            while (u && taken < NMASK_TOP) {
                unsigned bit = u & (~u + 1u);  // lowest set bit -> ascending index order
                uni++;
                if (both & bit) inter++;
                u ^= bit; taken++;
            }
        }
        float overlap = (float)inter / ((float)uni + 1e-6f);
        const float* fi = feats + (size_t)i * FDIM;
        const float* fj = feats + (size_t)j * FDIM;
        float dot = 0.0f;
#pragma unroll
        for (int d = 0; d < FDIM; ++d) dot += fi[d] * fj[d];
        float sim = (dot + 1.0f) / 2.0f;
        sim = fminf(fmaxf(sim, 0.0f), 1.0f);
        if (sim < 0.5f) sim = 1.0f;
        a = fmaxf(overlap * sim, a);
    }
    out[idx] = a;
}

extern "C" void kernel_launch(void* const* d_in, const int* in_sizes, int n_in,
                              void* d_out, int out_size, void* d_ws, size_t ws_size,
                              hipStream_t stream) {
    const float* pcds    = (const float*)d_in[0];
    // d_in[1] = spt_labels (unused: superpoints are contiguous groups of P)
    const void*  masks   = d_in[2];
    const int*   mapping = (const int*)d_in[3];
    const float* sam     = (const float*)d_in[4];
    const float* feas    = (const float*)d_in[5];
    float* out = (float*)d_out;

    char* ws = (char*)d_ws;
    size_t off = 0;
    auto take = [&](size_t bytes) -> void* {
        void* p = ws + off;
        off += (bytes + 255) & ~(size_t)255;
        return p;
    };
    float*    reps      = (float*)take((size_t)SPTS * KFPS * 3 * sizeof(float));
    int*      counts    = (int*)take((size_t)SPTS * NMSK * sizeof(int));
    unsigned* contrib   = (unsigned*)take((size_t)SPTS * 4 * sizeof(unsigned));
    float*    frac_kept = (float*)take((size_t)SPTS * NMSK * sizeof(float));
    float*    feats     = (float*)take((size_t)SPTS * FDIM * sizeof(float));
    unsigned* maskbits  = (unsigned*)take((size_t)HWPIX * 4 * sizeof(unsigned));
    size_t need_packed = off;
    int packed = (ws_size >= need_packed) ? 1 : 0;

    // Node 1: repack (blocks 0..511) || FPS (blocks 512..639)
    k_repack_fps<<<640, 256, 0, stream>>>(masks, maskbits, pcds, reps);
    // Node 2: coverage counts + superpoint features
    k_counts_feats<<<SPTS, PPS, 0, stream>>>(mapping, maskbits, masks, packed, feas,
                                             counts, contrib, feats);
    // Node 3: stable per-mask top-k -> contrib bits + frac_kept
    k_topk<<<NMSK, SPTS, 0, stream>>>(counts, contrib, frac_kept);
    // Node 4: adjacency + modulation + confidence
    k_adjmod<<<(SPTS * SPTS) / 256 + 2, 256, 0, stream>>>(reps, contrib, feats, frac_kept, sam, out);
}